// Round 1
// baseline (652.474 us; speedup 1.0000x reference)
//
#include <hip/hip_runtime.h>
#include <hip/hip_bf16.h>

// GRU policy: B=2048, T=512, V=4, E=64, H=128.
// Key structure: V=4 -> input-side projections collapse to a [4][384] table.
// Recurrence: 512 sequential steps of [16x128]@[128x384] bf16 MFMA per block.
// Block = 16 batch rows, 8 waves. Wave w owns gh cols [16w,16w+16) of r,z,n
// -> gates fully in-register (MFMA C layout col=lane&15, row=quad*4+reg).
// h double-buffered in LDS (bf16), 1 barrier/step. W_hh held in 48 VGPRs.

#define B_  2048
#define T_  512
#define V_  4
#define E_  64
#define H_  128
#define G3  384           // 3*H
#define SH  136           // h row stride in bf16 elems (128 + 8 pad), 272 B (16B-aligned rows)

typedef __attribute__((ext_vector_type(8))) short  short8;   // 8 bf16 = 4 VGPRs
typedef __attribute__((ext_vector_type(4))) float  float4v;

__device__ __forceinline__ short f32_to_bf16_rne(float f) {
  union { float ff; unsigned int u; } c; c.ff = f;
  unsigned int u = c.u + 0x7fffu + ((c.u >> 16) & 1u);
  return (short)(u >> 16);
}

// table[v][g] = b_ih[g] + sum_e W_ih[g,e]*emb[v,e]  (+ b_hh[g] folded for g<256)
__global__ void gi_table_kernel(const float* __restrict__ emb,
                                const float* __restrict__ W_ih,
                                const float* __restrict__ b_ih,
                                const float* __restrict__ b_hh,
                                float* __restrict__ table) {
  int gid = blockIdx.x * blockDim.x + threadIdx.x;
  if (gid >= V_ * G3) return;
  int v = gid / G3;
  int g = gid - v * G3;
  float acc = b_ih[g];
  if (g < 2 * H_) acc += b_hh[g];           // fold b_hh into r,z (NOT n: n needs r*gh_n)
  const float* wr = W_ih + g * E_;
  const float* er = emb + v * E_;
#pragma unroll 8
  for (int e = 0; e < E_; ++e) acc += wr[e] * er[e];
  table[gid] = acc;
}

__global__ __launch_bounds__(512) void gru_kernel(
    const int* __restrict__ x, const float* __restrict__ W_hh,
    const float* __restrict__ b_hh, const float* __restrict__ W_fc,
    const float* __restrict__ b_fc, const float* __restrict__ table,
    float* __restrict__ out) {
  __shared__ __align__(16) short hbuf[2][16 * SH];        // bf16 h, double-buffered
  __shared__ __align__(16) unsigned char xs[T_ * 16];     // x staged as [t][row] bytes (8 KB)

  const int tid  = threadIdx.x;
  const int w    = tid >> 6;      // wave 0..7
  const int lane = tid & 63;
  const int m    = lane & 15;     // MFMA "lane&15" index
  const int q    = lane >> 4;     // quad 0..3
  const int g0   = blockIdx.x * 16;  // batch base row

  // ---- stage x -> xs[t][r] (coalesced over t) ----
  for (int i = tid; i < 16 * T_; i += 512) {
    int r = i >> 9;               // 0..15
    int t = i & (T_ - 1);
    xs[t * 16 + r] = (unsigned char)(x[(g0 + r) * T_ + t] & 3);
  }
  // zero h buffer 0 (h0 = 0)
  for (int i = tid; i < 16 * SH; i += 512) hbuf[0][i] = 0;

  // ---- W_hh B-fragments, resident in registers all 512 steps ----
  // B[k][n]: n = lane&15 (gate col), k = quad*8 + j. Tile s covers g = s*128 + 16w + n.
  short8 bfrag[3][4];
#pragma unroll
  for (int s = 0; s < 3; ++s) {
    int g = s * H_ + w * 16 + m;
#pragma unroll
    for (int ks = 0; ks < 4; ++ks) {
      int k0 = ks * 32 + q * 8;
      const float* src = W_hh + g * H_ + k0;
      short8 f;
#pragma unroll
      for (int jj = 0; jj < 8; ++jj) f[jj] = f32_to_bf16_rne(src[jj]);
      bfrag[s][ks] = f;
    }
  }

  // ---- per-lane gi table (col j fixed per lane; only v=x[b,t] varies) ----
  const int j = w * 16 + m;       // h-column this lane owns in the gate phase
  float gr[4], gz[4], gn[4];
#pragma unroll
  for (int v = 0; v < 4; ++v) {
    gr[v] = table[v * G3 + j];
    gz[v] = table[v * G3 + H_ + j];
    gn[v] = table[v * G3 + 2 * H_ + j];
  }
  const float bhn = b_hh[2 * H_ + j];

  float h_old[4] = {0.f, 0.f, 0.f, 0.f};  // fp32 h for rows q*4+i, col j

  __syncthreads();

  // ---- recurrence: 512 steps, 1 barrier each ----
  for (int t = 0; t < T_; ++t) {
    const short* hb = hbuf[t & 1];
    short*       hn = hbuf[(t & 1) ^ 1];

    // A-frags: A[m][k], m=lane&15 (batch row), k=quad*8+j. 4 x ds_read_b128.
    short8 afrag[4];
#pragma unroll
    for (int ks = 0; ks < 4; ++ks)
      afrag[ks] = *(const short8*)(hb + m * SH + q * 8 + ks * 32);

    float4v acc[3];
#pragma unroll
    for (int s = 0; s < 3; ++s) {
      float4v a = {0.f, 0.f, 0.f, 0.f};
#pragma unroll
      for (int ks = 0; ks < 4; ++ks)
        a = __builtin_amdgcn_mfma_f32_16x16x32_bf16(afrag[ks], bfrag[s][ks], a, 0, 0, 0);
      acc[s] = a;
    }

    // token ids for this lane's 4 rows (broadcast-friendly b32 read)
    unsigned int xv = *(const unsigned int*)(xs + t * 16 + q * 4);

#pragma unroll
    for (int i = 0; i < 4; ++i) {
      int v = (int)((xv >> (8 * i)) & 3u);
      bool hi  = v >= 2;
      bool odd = (v & 1) != 0;
      float gir = odd ? (hi ? gr[3] : gr[1]) : (hi ? gr[2] : gr[0]);
      float giz = odd ? (hi ? gz[3] : gz[1]) : (hi ? gz[2] : gz[0]);
      float gin = odd ? (hi ? gn[3] : gn[1]) : (hi ? gn[2] : gn[0]);

      float rr = 1.f / (1.f + __expf(-(gir + acc[0][i])));       // b_hh_r folded in table
      float zz = 1.f / (1.f + __expf(-(giz + acc[1][i])));
      float npre = gin + rr * (acc[2][i] + bhn);
      float e2 = __expf(2.f * npre);
      float nn = 1.f - 2.f / (e2 + 1.f);                         // tanh, inf-safe
      float hnew = nn + zz * (h_old[i] - nn);                    // (1-z)n + z h
      h_old[i] = hnew;
      hn[(q * 4 + i) * SH + j] = f32_to_bf16_rne(hnew);
    }
    __syncthreads();   // writes to hn visible; next step reads hn, writes hb
  }

  // ---- epilogue: logits = hT @ W_fc^T + b_fc (reuse xs as fp32 h[16][128]) ----
  float* hf = (float*)(void*)xs;   // 16*128*4 = 8192 B, exactly xs size
#pragma unroll
  for (int i = 0; i < 4; ++i) hf[(q * 4 + i) * H_ + j] = h_old[i];
  __syncthreads();

  if (tid < 64) {
    int row = tid >> 2, vo = tid & 3;
    float s = b_fc[vo];
    const float* wv = W_fc + vo * H_;
#pragma unroll 8
    for (int k = 0; k < H_; ++k) s += hf[row * H_ + k] * wv[k];
    out[(g0 + row) * V_ + vo] = s;
  }
}

extern "C" void kernel_launch(void* const* d_in, const int* in_sizes, int n_in,
                              void* d_out, int out_size, void* d_ws, size_t ws_size,
                              hipStream_t stream) {
  const int*   x    = (const int*)d_in[0];
  const float* emb  = (const float*)d_in[1];
  const float* W_ih = (const float*)d_in[2];
  const float* W_hh = (const float*)d_in[3];
  const float* b_ih = (const float*)d_in[4];
  const float* b_hh = (const float*)d_in[5];
  const float* W_fc = (const float*)d_in[6];
  const float* b_fc = (const float*)d_in[7];
  float* out   = (float*)d_out;
  float* table = (float*)d_ws;   // 4*384 fp32 = 6 KB

  gi_table_kernel<<<(V_ * G3 + 255) / 256, 256, 0, stream>>>(emb, W_ih, b_ih, b_hh, table);
  gru_kernel<<<B_ / 16, 512, 0, stream>>>(x, W_hh, b_hh, W_fc, b_fc, table, out);
}

// Round 2
// 387.565 us; speedup vs baseline: 1.6835x; 1.6835x over previous
//
#include <hip/hip_runtime.h>
#include <hip/hip_bf16.h>

// GRU policy: B=2048, T=512, V=4, E=64, H=128.
// R1: (1) rcpf instead of precise fp32 divide (was ~216 inst/lane-step!),
//     (2) gi-lookup fused into MFMA via one-hot(token) @ table (K=32, 4 valid),
//     (3) swapped MFMA roles: A=W_hh, B=h, C=gh^T -> lane owns 4 CONTIGUOUS
//         gate cols for one batch row -> h writeback = one ds_write_b64.
// Per wave/step: 15 MFMA, 4 ds_read_b128 + 1 ds_read_b64 + 1 ds_write_b64,
// ~110 VALU inst (24 transcendental). 1 barrier/step.

#define B_  2048
#define T_  512
#define V_  4
#define E_  64
#define H_  128
#define G3  384
#define SH  144            // h row stride (bf16 elems): 288 B rows, 16B aligned
#define TC  128            // timestep chunk for one-hot staging
#define ZIDX (TC * 16)     // zero slot index in ohbuf

typedef __attribute__((ext_vector_type(8))) short  short8;   // 8 bf16
typedef __attribute__((ext_vector_type(4))) float  float4v;
typedef unsigned long long ull;

__device__ __forceinline__ unsigned int bf16r(float f) {   // RNE bits in high 16
  union { float ff; unsigned int u; } c; c.ff = f;
  return c.u + 0x7fffu + ((c.u >> 16) & 1u);
}
__device__ __forceinline__ short bf16s(float f) { return (short)(bf16r(f) >> 16); }

// table[v][g] = b_ih[g] + sum_e W_ih[g,e]*emb[v,e]  (+ b_hh[g] folded for g<2H)
__global__ void gi_table_kernel(const float* __restrict__ emb,
                                const float* __restrict__ W_ih,
                                const float* __restrict__ b_ih,
                                const float* __restrict__ b_hh,
                                float* __restrict__ table) {
  int gid = blockIdx.x * blockDim.x + threadIdx.x;
  if (gid >= V_ * G3) return;
  int v = gid / G3;
  int g = gid - v * G3;
  float acc = b_ih[g];
  if (g < 2 * H_) acc += b_hh[g];          // fold b_hh into r,z (NOT n)
  const float* wr = W_ih + g * E_;
  const float* er = emb + v * E_;
#pragma unroll 8
  for (int e = 0; e < E_; ++e) acc += wr[e] * er[e];
  table[gid] = acc;
}

__global__ __launch_bounds__(512) void gru_kernel(
    const int* __restrict__ x, const float* __restrict__ W_hh,
    const float* __restrict__ b_hh, const float* __restrict__ W_fc,
    const float* __restrict__ b_fc, const float* __restrict__ table,
    float* __restrict__ out) {
  __shared__ __align__(16) short hbuf[2][16 * SH];     // bf16 h, double-buffered
  __shared__ __align__(16) ull   ohbuf[TC * 16 + 1];   // one-hot B-frag per (t,row)
  __shared__ __align__(16) float hf[16 * H_];          // epilogue fp32 h

  const int tid  = threadIdx.x;
  const int w    = tid >> 6;        // wave 0..7
  const int lane = tid & 63;
  const int m    = lane & 15;       // batch row (B-col / C-col) and A gate-row
  const int q    = lane >> 4;       // quad
  const int g0   = blockIdx.x * 16;

  // ---- persistent A-fragments: W_hh tiles, layout A[g=m][k=q*8+j] ----
  short8 wA[3][4];
#pragma unroll
  for (int s = 0; s < 3; ++s) {
    const float* wrow = W_hh + (s * H_ + w * 16 + m) * H_;
#pragma unroll
    for (int ks = 0; ks < 4; ++ks) {
      const float* p = wrow + ks * 32 + q * 8;
      short8 f;
#pragma unroll
      for (int jj = 0; jj < 8; ++jj) f[jj] = bf16s(p[jj]);
      wA[s][ks] = f;
    }
  }
  // table A-frags for the one-hot gi MFMA: A[g=m][k'=jj], k'<4 (q==0 lanes only)
  short8 tabA[3];
#pragma unroll
  for (int s = 0; s < 3; ++s) {
    short8 f = {0, 0, 0, 0, 0, 0, 0, 0};
    if (q == 0) {
#pragma unroll
      for (int jj = 0; jj < 4; ++jj)
        f[jj] = bf16s(table[jj * G3 + s * H_ + w * 16 + m]);
    }
    tabA[s] = f;
  }

  const int c0 = w * 16 + q * 4;    // this lane's gate-col base (within H)
  const float4v bhn4 = *(const float4v*)(b_hh + 2 * H_ + c0);
  float h_old[4] = {0.f, 0.f, 0.f, 0.f};

  for (int i = tid; i < 16 * SH; i += 512) hbuf[0][i] = 0;   // h0 = 0
  if (tid == 0) ohbuf[ZIDX] = 0ull;                          // zero one-hot slot

  const int ohinc = (q == 0) ? 16 : 0;
  const float4v zero4 = {0.f, 0.f, 0.f, 0.f};
  int ohidx = 0;

  auto step = [&](int FROM, int TO) {
    const short* rb = &hbuf[FROM][m * SH + q * 8];
    short8 h0 = *(const short8*)(rb);
    short8 h1 = *(const short8*)(rb + 32);
    short8 h2 = *(const short8*)(rb + 64);
    short8 h3 = *(const short8*)(rb + 96);
    union { short8 s; ull u[2]; } ohf;
    ohf.u[0] = ohbuf[ohidx];
    ohf.u[1] = 0ull;
    ohidx += ohinc;
    // gi via one-hot MFMA (starts each chain; n's gi must stay separate)
    float4v a0 = __builtin_amdgcn_mfma_f32_16x16x32_bf16(tabA[0], ohf.s, zero4, 0, 0, 0);
    float4v a1 = __builtin_amdgcn_mfma_f32_16x16x32_bf16(tabA[1], ohf.s, zero4, 0, 0, 0);
    float4v a3 = __builtin_amdgcn_mfma_f32_16x16x32_bf16(tabA[2], ohf.s, zero4, 0, 0, 0);
    // gh = W_hh @ h^T
    float4v a2 = __builtin_amdgcn_mfma_f32_16x16x32_bf16(wA[2][0], h0, zero4, 0, 0, 0);
    a0 = __builtin_amdgcn_mfma_f32_16x16x32_bf16(wA[0][0], h0, a0, 0, 0, 0);
    a1 = __builtin_amdgcn_mfma_f32_16x16x32_bf16(wA[1][0], h0, a1, 0, 0, 0);
    a0 = __builtin_amdgcn_mfma_f32_16x16x32_bf16(wA[0][1], h1, a0, 0, 0, 0);
    a1 = __builtin_amdgcn_mfma_f32_16x16x32_bf16(wA[1][1], h1, a1, 0, 0, 0);
    a2 = __builtin_amdgcn_mfma_f32_16x16x32_bf16(wA[2][1], h1, a2, 0, 0, 0);
    a0 = __builtin_amdgcn_mfma_f32_16x16x32_bf16(wA[0][2], h2, a0, 0, 0, 0);
    a1 = __builtin_amdgcn_mfma_f32_16x16x32_bf16(wA[1][2], h2, a1, 0, 0, 0);
    a2 = __builtin_amdgcn_mfma_f32_16x16x32_bf16(wA[2][2], h2, a2, 0, 0, 0);
    a0 = __builtin_amdgcn_mfma_f32_16x16x32_bf16(wA[0][3], h3, a0, 0, 0, 0);
    a1 = __builtin_amdgcn_mfma_f32_16x16x32_bf16(wA[1][3], h3, a1, 0, 0, 0);
    a2 = __builtin_amdgcn_mfma_f32_16x16x32_bf16(wA[2][3], h3, a2, 0, 0, 0);

    unsigned int rb_[4];
#pragma unroll
    for (int i = 0; i < 4; ++i) {
      float r  = __builtin_amdgcn_rcpf(1.f + __expf(-a0[i]));
      float z  = __builtin_amdgcn_rcpf(1.f + __expf(-a1[i]));
      float gh = a2[i] + bhn4[i];
      float np = __fmaf_rn(r, gh, a3[i]);
      float e2 = __expf(np + np);
      float nn = __fmaf_rn(-2.f, __builtin_amdgcn_rcpf(e2 + 1.f), 1.f);
      float hn = __fmaf_rn(z, h_old[i] - nn, nn);
      h_old[i] = hn;
      rb_[i] = bf16r(hn);
    }
    unsigned int pk0 = (rb_[0] >> 16) | (rb_[1] & 0xffff0000u);
    unsigned int pk1 = (rb_[2] >> 16) | (rb_[3] & 0xffff0000u);
    *(ull*)(&hbuf[TO][m * SH + c0]) = ((ull)pk1 << 32) | pk0;
    __syncthreads();
  };

  for (int c = 0; c < 4; ++c) {
    // ---- refill one-hot staging for this 128-step chunk ----
    {
      int mm = tid >> 5, u = tid & 31;
      int4 xv = *(const int4*)(x + (g0 + mm) * T_ + c * TC + u * 4);
      int vs[4] = {xv.x, xv.y, xv.z, xv.w};
#pragma unroll
      for (int e = 0; e < 4; ++e) {
        int v = vs[e] & 3;
        unsigned int d0 = (v == 0) ? 0x3F80u : (v == 1) ? 0x3F800000u : 0u;
        unsigned int d1 = (v == 2) ? 0x3F80u : (v == 3) ? 0x3F800000u : 0u;
        ohbuf[(u * 4 + e) * 16 + mm] = ((ull)d1 << 32) | d0;
      }
    }
    __syncthreads();
    ohidx = (q == 0) ? m : ZIDX;
    for (int tc = 0; tc < TC; tc += 2) {
      step(0, 1);
      step(1, 0);
    }
  }

  // ---- epilogue: logits = hT @ W_fc^T + b_fc ----
  float4v hv;
#pragma unroll
  for (int i = 0; i < 4; ++i) hv[i] = h_old[i];
  *(float4v*)(&hf[m * H_ + c0]) = hv;
  __syncthreads();

  if (tid < 64) {
    int row = tid >> 2, vo = tid & 3;
    float s = b_fc[vo];
    const float* wv = W_fc + vo * H_;
    const float* hr = &hf[row * H_];
#pragma unroll 4
    for (int k = 0; k < H_; k += 4)
      s += hr[k] * wv[k] + hr[k + 1] * wv[k + 1]
         + hr[k + 2] * wv[k + 2] + hr[k + 3] * wv[k + 3];
    out[(g0 + row) * V_ + vo] = s;
  }
}

extern "C" void kernel_launch(void* const* d_in, const int* in_sizes, int n_in,
                              void* d_out, int out_size, void* d_ws, size_t ws_size,
                              hipStream_t stream) {
  const int*   x    = (const int*)d_in[0];
  const float* emb  = (const float*)d_in[1];
  const float* W_ih = (const float*)d_in[2];
  const float* W_hh = (const float*)d_in[3];
  const float* b_ih = (const float*)d_in[4];
  const float* b_hh = (const float*)d_in[5];
  const float* W_fc = (const float*)d_in[6];
  const float* b_fc = (const float*)d_in[7];
  float* out   = (float*)d_out;
  float* table = (float*)d_ws;     // 4*384 fp32 = 6 KB

  gi_table_kernel<<<(V_ * G3 + 255) / 256, 256, 0, stream>>>(emb, W_ih, b_ih, b_hh, table);
  gru_kernel<<<B_ / 16, 512, 0, stream>>>(x, W_hh, b_hh, W_fc, b_fc, table, out);
}

// Round 3
// 358.143 us; speedup vs baseline: 1.8218x; 1.0822x over previous
//
#include <hip/hip_runtime.h>
#include <hip/hip_bf16.h>

// GRU policy: B=2048, T=512, V=4, E=64, H=128.
// R2: (1) MFMA chain reorder: r/z accumulators complete FIRST, n-chains issued
//         before r/z sigmoid VALU -> trans ops overlap matrix-pipe drain.
//     (2) exp2 pre-scaling: r,z rows of table/W_hh scaled by -log2e, n rows by
//         2*log2e -> raw v_exp_f32, no mul/neg, tanh without the *2.
//     (3) bf16 pack via +0x8000 round + v_perm_b32 (6 inst vs ~20).
// Per wave/step: 15 MFMA, 4 ds_read_b128 + 1 ds_read_b64 + 1 ds_write_b64,
// ~62 VALU inst (16 trans). 1 barrier/step. 128 blocks (structural).

#define B_  2048
#define T_  512
#define V_  4
#define E_  64
#define H_  128
#define G3  384
#define SH  144            // h row stride (bf16 elems): 288 B rows, 16B aligned
#define TC  128            // timestep chunk for one-hot staging
#define ZIDX (TC * 16)     // zero slot index in ohbuf

#define LOG2E 1.4426950408889634f

typedef __attribute__((ext_vector_type(8))) short  short8;   // 8 bf16
typedef __attribute__((ext_vector_type(4))) float  float4v;
typedef unsigned long long ull;

__device__ __forceinline__ short bf16s(float f) {            // RNE scalar (setup only)
  union { float ff; unsigned int u; } c; c.ff = f;
  return (short)((c.u + 0x7fffu + ((c.u >> 16) & 1u)) >> 16);
}

// table[v][g] = scale_g * (b_ih[g] + sum_e W_ih[g,e]*emb[v,e] (+ b_hh[g] for g<2H))
// scale_g = -log2e for r,z rows; +2*log2e for n rows (b_hh_n NOT folded).
__global__ void gi_table_kernel(const float* __restrict__ emb,
                                const float* __restrict__ W_ih,
                                const float* __restrict__ b_ih,
                                const float* __restrict__ b_hh,
                                float* __restrict__ table) {
  int gid = blockIdx.x * blockDim.x + threadIdx.x;
  if (gid >= V_ * G3) return;
  int v = gid / G3;
  int g = gid - v * G3;
  float acc = b_ih[g];
  if (g < 2 * H_) acc += b_hh[g];
  const float* wr = W_ih + g * E_;
  const float* er = emb + v * E_;
#pragma unroll 8
  for (int e = 0; e < E_; ++e) acc += wr[e] * er[e];
  table[gid] = acc * ((g < 2 * H_) ? -LOG2E : 2.f * LOG2E);
}

__global__ __launch_bounds__(512) void gru_kernel(
    const int* __restrict__ x, const float* __restrict__ W_hh,
    const float* __restrict__ b_hh, const float* __restrict__ W_fc,
    const float* __restrict__ b_fc, const float* __restrict__ table,
    float* __restrict__ out) {
  __shared__ __align__(16) short hbuf[2][16 * SH];     // bf16 h, double-buffered
  __shared__ __align__(16) ull   ohbuf[TC * 16 + 1];   // one-hot B-frag per (t,row)
  __shared__ __align__(16) float hf[16 * H_];          // epilogue fp32 h

  const int tid  = threadIdx.x;
  const int w    = tid >> 6;        // wave 0..7
  const int lane = tid & 63;
  const int m    = lane & 15;       // batch row (B/C col) and A gate-row
  const int q    = lane >> 4;       // quad
  const int g0   = blockIdx.x * 16;

  // ---- persistent A-fragments: W_hh tiles (pre-scaled), A[g=m][k=q*8+j] ----
  short8 wA[3][4];
#pragma unroll
  for (int s = 0; s < 3; ++s) {
    const float sc = (s < 2) ? -LOG2E : 2.f * LOG2E;
    const float* wrow = W_hh + (s * H_ + w * 16 + m) * H_;
#pragma unroll
    for (int ks = 0; ks < 4; ++ks) {
      const float* p = wrow + ks * 32 + q * 8;
      short8 f;
#pragma unroll
      for (int jj = 0; jj < 8; ++jj) f[jj] = bf16s(p[jj] * sc);
      wA[s][ks] = f;
    }
  }
  // table A-frags for the one-hot gi MFMA (q==0 lanes hold k'=0..3)
  short8 tabA[3];
#pragma unroll
  for (int s = 0; s < 3; ++s) {
    short8 f = {0, 0, 0, 0, 0, 0, 0, 0};
    if (q == 0) {
#pragma unroll
      for (int jj = 0; jj < 4; ++jj)
        f[jj] = bf16s(table[jj * G3 + s * H_ + w * 16 + m]);
    }
    tabA[s] = f;
  }

  const int c0 = w * 16 + q * 4;    // this lane's h-col base
  float4v bhn4;
  {
    const float* p = b_hh + 2 * H_ + c0;
#pragma unroll
    for (int i = 0; i < 4; ++i) bhn4[i] = p[i] * 2.f * LOG2E;
  }
  float h_old[4] = {0.f, 0.f, 0.f, 0.f};

  for (int i = tid; i < 16 * SH; i += 512) hbuf[0][i] = 0;   // h0 = 0
  if (tid == 0) ohbuf[ZIDX] = 0ull;

  const int ohinc = (q == 0) ? 16 : 0;
  const float4v zero4 = {0.f, 0.f, 0.f, 0.f};
  int ohidx = 0;

  auto step = [&](int FROM, int TO) {
    const short* rbp = &hbuf[FROM][m * SH + q * 8];
    short8 h0 = *(const short8*)(rbp);
    short8 h1 = *(const short8*)(rbp + 32);
    short8 h2 = *(const short8*)(rbp + 64);
    short8 h3 = *(const short8*)(rbp + 96);
    union { short8 s; ull u[2]; } ohf;
    ohf.u[0] = ohbuf[ohidx];
    ohf.u[1] = 0ull;
    ohidx += ohinc;

    // r/z chains first (2-way interleaved), so a0/a1 complete earliest
    float4v a0 = __builtin_amdgcn_mfma_f32_16x16x32_bf16(tabA[0], ohf.s, zero4, 0, 0, 0);
    float4v a1 = __builtin_amdgcn_mfma_f32_16x16x32_bf16(tabA[1], ohf.s, zero4, 0, 0, 0);
    a0 = __builtin_amdgcn_mfma_f32_16x16x32_bf16(wA[0][0], h0, a0, 0, 0, 0);
    a1 = __builtin_amdgcn_mfma_f32_16x16x32_bf16(wA[1][0], h0, a1, 0, 0, 0);
    a0 = __builtin_amdgcn_mfma_f32_16x16x32_bf16(wA[0][1], h1, a0, 0, 0, 0);
    a1 = __builtin_amdgcn_mfma_f32_16x16x32_bf16(wA[1][1], h1, a1, 0, 0, 0);
    a0 = __builtin_amdgcn_mfma_f32_16x16x32_bf16(wA[0][2], h2, a0, 0, 0, 0);
    a1 = __builtin_amdgcn_mfma_f32_16x16x32_bf16(wA[1][2], h2, a1, 0, 0, 0);
    a0 = __builtin_amdgcn_mfma_f32_16x16x32_bf16(wA[0][3], h3, a0, 0, 0, 0);
    a1 = __builtin_amdgcn_mfma_f32_16x16x32_bf16(wA[1][3], h3, a1, 0, 0, 0);
    // n chains issued before r/z VALU -> matrix pipe drains under the trans ops
    float4v a3 = __builtin_amdgcn_mfma_f32_16x16x32_bf16(tabA[2], ohf.s, zero4, 0, 0, 0);
    float4v a2 = __builtin_amdgcn_mfma_f32_16x16x32_bf16(wA[2][0], h0, zero4, 0, 0, 0);
    a2 = __builtin_amdgcn_mfma_f32_16x16x32_bf16(wA[2][1], h1, a2, 0, 0, 0);
    a2 = __builtin_amdgcn_mfma_f32_16x16x32_bf16(wA[2][2], h2, a2, 0, 0, 0);
    a2 = __builtin_amdgcn_mfma_f32_16x16x32_bf16(wA[2][3], h3, a2, 0, 0, 0);

    // r, z: depend only on a0/a1 (pre-scaled by -log2e: exp2(a0)=e^-x)
    float r[4], z[4];
#pragma unroll
    for (int i = 0; i < 4; ++i) {
      r[i] = __builtin_amdgcn_rcpf(1.f + __builtin_amdgcn_exp2f(a0[i]));
      z[i] = __builtin_amdgcn_rcpf(1.f + __builtin_amdgcn_exp2f(a1[i]));
    }
    // n, h: depend on a2/a3 (pre-scaled by 2*log2e: exp2(np')=e^{2np})
    unsigned int rb_[4];
#pragma unroll
    for (int i = 0; i < 4; ++i) {
      float np = __fmaf_rn(r[i], a2[i] + bhn4[i], a3[i]);
      float e2 = __builtin_amdgcn_exp2f(np);
      float nn = __fmaf_rn(-2.f, __builtin_amdgcn_rcpf(e2 + 1.f), 1.f);
      float hn = __fmaf_rn(z[i], h_old[i] - nn, nn);
      h_old[i] = hn;
      union { float ff; unsigned int u; } c; c.ff = hn;
      rb_[i] = c.u + 0x8000u;                      // round-half-up to bf16
    }
    unsigned int pk0 = __builtin_amdgcn_perm(rb_[1], rb_[0], 0x07060302u);
    unsigned int pk1 = __builtin_amdgcn_perm(rb_[3], rb_[2], 0x07060302u);
    *(ull*)(&hbuf[TO][m * SH + c0]) = ((ull)pk1 << 32) | pk0;
    __syncthreads();
  };

  for (int c = 0; c < 4; ++c) {
    // ---- refill one-hot staging for this 128-step chunk ----
    {
      int mm = tid >> 5, u = tid & 31;
      int4 xv = *(const int4*)(x + (g0 + mm) * T_ + c * TC + u * 4);
      int vs[4] = {xv.x, xv.y, xv.z, xv.w};
#pragma unroll
      for (int e = 0; e < 4; ++e) {
        int v = vs[e] & 3;
        unsigned int d0 = (v == 0) ? 0x3F80u : (v == 1) ? 0x3F800000u : 0u;
        unsigned int d1 = (v == 2) ? 0x3F80u : (v == 3) ? 0x3F800000u : 0u;
        ohbuf[(u * 4 + e) * 16 + mm] = ((ull)d1 << 32) | d0;
      }
    }
    __syncthreads();
    ohidx = (q == 0) ? m : ZIDX;
    for (int tc = 0; tc < TC; tc += 2) {
      step(0, 1);
      step(1, 0);
    }
  }

  // ---- epilogue: logits = hT @ W_fc^T + b_fc ----
  float4v hv;
#pragma unroll
  for (int i = 0; i < 4; ++i) hv[i] = h_old[i];
  *(float4v*)(&hf[m * H_ + c0]) = hv;
  __syncthreads();

  if (tid < 64) {
    int row = tid >> 2, vo = tid & 3;
    float s = b_fc[vo];
    const float* wv = W_fc + vo * H_;
    const float* hr = &hf[row * H_];
#pragma unroll 4
    for (int k = 0; k < H_; k += 4)
      s += hr[k] * wv[k] + hr[k + 1] * wv[k + 1]
         + hr[k + 2] * wv[k + 2] + hr[k + 3] * wv[k + 3];
    out[(g0 + row) * V_ + vo] = s;
  }
}

extern "C" void kernel_launch(void* const* d_in, const int* in_sizes, int n_in,
                              void* d_out, int out_size, void* d_ws, size_t ws_size,
                              hipStream_t stream) {
  const int*   x    = (const int*)d_in[0];
  const float* emb  = (const float*)d_in[1];
  const float* W_ih = (const float*)d_in[2];
  const float* W_hh = (const float*)d_in[3];
  const float* b_ih = (const float*)d_in[4];
  const float* b_hh = (const float*)d_in[5];
  const float* W_fc = (const float*)d_in[6];
  const float* b_fc = (const float*)d_in[7];
  float* out   = (float*)d_out;
  float* table = (float*)d_ws;     // 4*384 fp32 = 6 KB

  gi_table_kernel<<<(V_ * G3 + 255) / 256, 256, 0, stream>>>(emb, W_ih, b_ih, b_hh, table);
  gru_kernel<<<B_ / 16, 512, 0, stream>>>(x, W_hh, b_hh, W_fc, b_fc, table, out);
}

// Round 5
// 357.392 us; speedup vs baseline: 1.8257x; 1.0021x over previous
//
#include <hip/hip_runtime.h>
#include <hip/hip_bf16.h>

// GRU policy: B=2048, T=512, V=4, E=64, H=128.
// R4 (= R3 with the stray '#pragma unroll' compile fix):
//     (1) one-hot frag software-pipelined one step ahead -> the 3 h-independent
//         one-hot MFMAs issue at barrier exit, covering h ds_read latency.
//     (2) antiphase wave scheduling: even waves (a0|a1 -> r,z -> a2 -> n),
//         odd waves (a0|a2 -> r,n -> a1 -> z). Same math, phase-shifted ->
//         one wave's trans VALU overlaps the partner wave's MFMA drain.
//     (3) SH 144->136 (min-aliasing LDS patterns, 16B-aligned b128 reads).
// Per wave/step: 15 MFMA, 4 ds_read_b128 + 1 ds_read_b64 + 1 ds_write_b64,
// ~62 VALU inst (24 trans). 1 barrier/step. 128 blocks (structural: B/16).

#define B_  2048
#define T_  512
#define V_  4
#define E_  64
#define H_  128
#define G3  384
#define SH  136            // h row stride (bf16 elems): 272 B rows, 16B aligned
#define TC  128            // timestep chunk for one-hot staging
#define ZIDX (TC * 16)     // zero slot index in ohbuf (stays 0; refills never touch)

#define LOG2E 1.4426950408889634f

typedef __attribute__((ext_vector_type(8))) short  short8;   // 8 bf16
typedef __attribute__((ext_vector_type(4))) float  float4v;
typedef unsigned long long ull;

__device__ __forceinline__ short bf16s(float f) {            // RNE scalar (setup only)
  union { float ff; unsigned int u; } c; c.ff = f;
  return (short)((c.u + 0x7fffu + ((c.u >> 16) & 1u)) >> 16);
}

// table[v][g] = scale_g * (b_ih[g] + sum_e W_ih[g,e]*emb[v,e] (+ b_hh[g] for g<2H))
// scale_g = -log2e for r,z rows; +2*log2e for n rows (b_hh_n NOT folded).
__global__ void gi_table_kernel(const float* __restrict__ emb,
                                const float* __restrict__ W_ih,
                                const float* __restrict__ b_ih,
                                const float* __restrict__ b_hh,
                                float* __restrict__ table) {
  int gid = blockIdx.x * blockDim.x + threadIdx.x;
  if (gid >= V_ * G3) return;
  int v = gid / G3;
  int g = gid - v * G3;
  float acc = b_ih[g];
  if (g < 2 * H_) acc += b_hh[g];
  const float* wr = W_ih + g * E_;
  const float* er = emb + v * E_;
#pragma unroll 8
  for (int e = 0; e < E_; ++e) acc += wr[e] * er[e];
  table[gid] = acc * ((g < 2 * H_) ? -LOG2E : 2.f * LOG2E);
}

#define MFMA16(A, B, C) __builtin_amdgcn_mfma_f32_16x16x32_bf16((A), (B), (C), 0, 0, 0)

__global__ __launch_bounds__(512) void gru_kernel(
    const int* __restrict__ x, const float* __restrict__ W_hh,
    const float* __restrict__ b_hh, const float* __restrict__ W_fc,
    const float* __restrict__ b_fc, const float* __restrict__ table,
    float* __restrict__ out) {
  __shared__ __align__(16) short hbuf[2][16 * SH];       // bf16 h, double-buffered
  __shared__ __align__(16) ull   ohbuf[TC * 16 + 32];    // one-hot per (t,row) + zero/pad
  __shared__ __align__(16) float hf[16 * H_];            // epilogue fp32 h

  const int tid  = threadIdx.x;
  const int w    = tid >> 6;        // wave 0..7
  const int lane = tid & 63;
  const int m    = lane & 15;       // batch row (B/C col) and A gate-row
  const int q    = lane >> 4;       // quad
  const int g0   = blockIdx.x * 16;

  // ---- persistent A-fragments: W_hh tiles (pre-scaled), A[g=m][k=q*8+j] ----
  short8 wA[3][4];
#pragma unroll
  for (int s = 0; s < 3; ++s) {
    const float sc = (s < 2) ? -LOG2E : 2.f * LOG2E;
    const float* wrow = W_hh + (s * H_ + w * 16 + m) * H_;
#pragma unroll
    for (int ks = 0; ks < 4; ++ks) {
      const float* p = wrow + ks * 32 + q * 8;
      short8 f;
#pragma unroll
      for (int jj = 0; jj < 8; ++jj) f[jj] = bf16s(p[jj] * sc);
      wA[s][ks] = f;
    }
  }
  // table A-frags for the one-hot gi MFMA (q==0 lanes hold k'=0..3)
  short8 tabA[3];
#pragma unroll
  for (int s = 0; s < 3; ++s) {
    short8 f = {0, 0, 0, 0, 0, 0, 0, 0};
    if (q == 0) {
#pragma unroll
      for (int jj = 0; jj < 4; ++jj)
        f[jj] = bf16s(table[jj * G3 + s * H_ + w * 16 + m]);
    }
    tabA[s] = f;
  }

  const int c0 = w * 16 + q * 4;    // this lane's h-col base
  float4v bhn4;
  {
    const float* p = b_hh + 2 * H_ + c0;
#pragma unroll
    for (int i = 0; i < 4; ++i) bhn4[i] = p[i] * 2.f * LOG2E;
  }
  float h_old[4] = {0.f, 0.f, 0.f, 0.f};

  for (int i = tid; i < 16 * SH; i += 512) hbuf[0][i] = 0;   // h0 = 0
  if (tid == 0) ohbuf[ZIDX] = 0ull;

  const int  ohinc = (q == 0) ? 16 : 0;
  const bool wodd  = (w & 1) != 0;
  const float4v zero4 = {0.f, 0.f, 0.f, 0.f};
  ull ohcur = 0;      // software-pipelined one-hot payload (loaded 1 step ahead)
  int ohidx = 0;

  auto step = [&](int FROM, int TO) {
    // 1) h reads first (latency covered by one-hot MFMAs below)
    const short* rbp = &hbuf[FROM][m * SH + q * 8];
    short8 h0 = *(const short8*)(rbp);
    short8 h1 = *(const short8*)(rbp + 32);
    short8 h2 = *(const short8*)(rbp + 64);
    short8 h3 = *(const short8*)(rbp + 96);

    // 2) one-hot MFMAs: ohcur was preloaded last step -> zero wait
    union { short8 s; ull u[2]; } ohf;
    ohf.u[0] = ohcur; ohf.u[1] = 0ull;
    float4v a0 = MFMA16(tabA[0], ohf.s, zero4);
    float4v a1 = MFMA16(tabA[1], ohf.s, zero4);
    float4v a3 = MFMA16(tabA[2], ohf.s, zero4);
    // preload next step's one-hot (pad slots absorb the last, unused, read)
    ohcur = ohbuf[ohidx];
    ohidx += ohinc;

    float4v a2;
    unsigned int rb_[4];
    if (!wodd) {
      // EVEN: a0|a1 -> r,z -> a2 -> n-tail
      a0 = MFMA16(wA[0][0], h0, a0); a1 = MFMA16(wA[1][0], h0, a1);
      a0 = MFMA16(wA[0][1], h1, a0); a1 = MFMA16(wA[1][1], h1, a1);
      a0 = MFMA16(wA[0][2], h2, a0); a1 = MFMA16(wA[1][2], h2, a1);
      a0 = MFMA16(wA[0][3], h3, a0); a1 = MFMA16(wA[1][3], h3, a1);
      a2 = MFMA16(wA[2][0], h0, zero4);
      a2 = MFMA16(wA[2][1], h1, a2);
      float r[4], z[4];
#pragma unroll
      for (int i = 0; i < 4; ++i) {
        r[i] = __builtin_amdgcn_rcpf(1.f + __builtin_amdgcn_exp2f(a0[i]));
        z[i] = __builtin_amdgcn_rcpf(1.f + __builtin_amdgcn_exp2f(a1[i]));
      }
      a2 = MFMA16(wA[2][2], h2, a2);
      a2 = MFMA16(wA[2][3], h3, a2);
#pragma unroll
      for (int i = 0; i < 4; ++i) {
        float np = __fmaf_rn(r[i], a2[i] + bhn4[i], a3[i]);
        float e2 = __builtin_amdgcn_exp2f(np);
        float nn = __fmaf_rn(-2.f, __builtin_amdgcn_rcpf(e2 + 1.f), 1.f);
        float hn = __fmaf_rn(z[i], h_old[i] - nn, nn);
        h_old[i] = hn;
        union { float ff; unsigned int u; } c; c.ff = hn;
        rb_[i] = c.u + 0x8000u;
      }
    } else {
      // ODD: a0|a2 -> r,n -> a1 -> z-tail
      a2 = MFMA16(wA[2][0], h0, zero4);
      a0 = MFMA16(wA[0][0], h0, a0); a2 = MFMA16(wA[2][1], h1, a2);
      a0 = MFMA16(wA[0][1], h1, a0); a2 = MFMA16(wA[2][2], h2, a2);
      a0 = MFMA16(wA[0][2], h2, a0); a2 = MFMA16(wA[2][3], h3, a2);
      a0 = MFMA16(wA[0][3], h3, a0);
      a1 = MFMA16(wA[1][0], h0, a1);
      a1 = MFMA16(wA[1][1], h1, a1);
      float nn4[4];
#pragma unroll
      for (int i = 0; i < 4; ++i) {
        float r  = __builtin_amdgcn_rcpf(1.f + __builtin_amdgcn_exp2f(a0[i]));
        float np = __fmaf_rn(r, a2[i] + bhn4[i], a3[i]);
        float e2 = __builtin_amdgcn_exp2f(np);
        nn4[i] = __fmaf_rn(-2.f, __builtin_amdgcn_rcpf(e2 + 1.f), 1.f);
      }
      a1 = MFMA16(wA[1][2], h2, a1);
      a1 = MFMA16(wA[1][3], h3, a1);
#pragma unroll
      for (int i = 0; i < 4; ++i) {
        float z  = __builtin_amdgcn_rcpf(1.f + __builtin_amdgcn_exp2f(a1[i]));
        float hn = __fmaf_rn(z, h_old[i] - nn4[i], nn4[i]);
        h_old[i] = hn;
        union { float ff; unsigned int u; } c; c.ff = hn;
        rb_[i] = c.u + 0x8000u;
      }
    }
    unsigned int pk0 = __builtin_amdgcn_perm(rb_[1], rb_[0], 0x07060302u);
    unsigned int pk1 = __builtin_amdgcn_perm(rb_[3], rb_[2], 0x07060302u);
    *(ull*)(&hbuf[TO][m * SH + c0]) = ((ull)pk1 << 32) | pk0;
    __syncthreads();
  };

  for (int c = 0; c < 4; ++c) {
    // ---- refill one-hot staging for this 128-step chunk ----
    {
      int mm = tid >> 5, u = tid & 31;
      int4 xv = *(const int4*)(x + (g0 + mm) * T_ + c * TC + u * 4);
      int vs[4] = {xv.x, xv.y, xv.z, xv.w};
#pragma unroll
      for (int e = 0; e < 4; ++e) {
        int v = vs[e] & 3;
        unsigned int d0 = (v == 0) ? 0x3F80u : (v == 1) ? 0x3F800000u : 0u;
        unsigned int d1 = (v == 2) ? 0x3F80u : (v == 3) ? 0x3F800000u : 0u;
        ohbuf[(u * 4 + e) * 16 + mm] = ((ull)d1 << 32) | d0;
      }
    }
    __syncthreads();
    ohidx = (q == 0) ? m : ZIDX;
    ohcur = ohbuf[ohidx];           // preload step 0 of this chunk
    ohidx += ohinc;
    for (int tc = 0; tc < TC; tc += 2) {
      step(0, 1);
      step(1, 0);
    }
  }

  // ---- epilogue: logits = hT @ W_fc^T + b_fc ----
  float4v hv;
#pragma unroll
  for (int i = 0; i < 4; ++i) hv[i] = h_old[i];
  *(float4v*)(&hf[m * H_ + c0]) = hv;
  __syncthreads();

  if (tid < 64) {
    int row = tid >> 2, vo = tid & 3;
    float s = b_fc[vo];
    const float* wv = W_fc + vo * H_;
    const float* hr = &hf[row * H_];
#pragma unroll 4
    for (int k = 0; k < H_; k += 4)
      s += hr[k] * wv[k] + hr[k + 1] * wv[k + 1]
         + hr[k + 2] * wv[k + 2] + hr[k + 3] * wv[k + 3];
    out[(g0 + row) * V_ + vo] = s;
  }
}

extern "C" void kernel_launch(void* const* d_in, const int* in_sizes, int n_in,
                              void* d_out, int out_size, void* d_ws, size_t ws_size,
                              hipStream_t stream) {
  const int*   x    = (const int*)d_in[0];
  const float* emb  = (const float*)d_in[1];
  const float* W_ih = (const float*)d_in[2];
  const float* W_hh = (const float*)d_in[3];
  const float* b_ih = (const float*)d_in[4];
  const float* b_hh = (const float*)d_in[5];
  const float* W_fc = (const float*)d_in[6];
  const float* b_fc = (const float*)d_in[7];
  float* out   = (float*)d_out;
  float* table = (float*)d_ws;     // 4*384 fp32 = 6 KB

  gi_table_kernel<<<(V_ * G3 + 255) / 256, 256, 0, stream>>>(emb, W_ih, b_ih, b_hh, table);
  gru_kernel<<<B_ / 16, 512, 0, stream>>>(x, W_hh, b_hh, W_fc, b_fc, table, out);
}